// Round 6
// baseline (182.785 us; speedup 1.0000x reference)
//
#include <hip/hip_runtime.h>

typedef _Float16 h4 __attribute__((ext_vector_type(4)));
typedef _Float16 h8 __attribute__((ext_vector_type(8)));
typedef float    f4 __attribute__((ext_vector_type(4)));

#define EXP2F(x) __builtin_amdgcn_exp2f(x)   // raw v_exp_f32 (compiles on this toolchain; R4 ran)

#define L_   2048
#define SR   512      // H*E row stride (elements)
#define QB   128      // q rows per block
#define QW   32       // q rows per wave

// ---- LDS layout (bytes) ----
#define OFF_K   0
#define KROWB   144                       // 64 f16 + 16 pad per K row
#define OFF_V   (64*KROWB)                // 9216
#define VTS     136                       // V^T row stride: 64 f16 + 8 pad (8B-aligned)
#define OFF_OB  (OFF_V + 64*VTS)          // 17920
#define OBSTR   272                       // 64 floats + 16B pad per q row
#define OBSZ    (16*OBSTR)                // 4352 per wave
#define LDS_TOTAL (OFF_OB + 4*OBSZ)       // 35328

__global__ __launch_bounds__(256, 2)
void fa_fwd_causal(const float* __restrict__ Qg, const float* __restrict__ Kg,
                   const float* __restrict__ Vg, float* __restrict__ Og) {
  __shared__ char smem[LDS_TOTAL] __attribute__((aligned(16)));

  // big causal tiles first, big+small paired per CU (qt(u)+qt(u+8)==15)
  const int bx = blockIdx.x;
  const int u  = bx >> 5;
  const int qt = (u < 8) ? (15 - 2*u) : (2*u - 16);
  const int bh = bx & 31;
  const int b  = bh >> 3, h = bh & 7;
  const int q0 = qt * QB;

  const int tid = threadIdx.x, lane = tid & 63, w = tid >> 6;
  const int l15 = lane & 15, g = lane >> 4;

  const size_t base = (size_t)b * (L_ * SR) + (size_t)h * 64;
  const float* Qb = Qg + base;
  const float* Kb = Kg + base;
  const float* Vb = Vg + base;
  float*       Ob = Og + base;

  const int qw = q0 + w * QW, qmaxw = qw + QW - 1;

  // ---- Q frags: fp32 -> f16, scale*log2(e) folded in ----
  const float SC = 0.125f * 1.44269504088896340736f;
  h8 qf[2][2];                                      // [qs][es]
#pragma unroll
  for (int qs = 0; qs < 2; ++qs) {
    const float* qp0 = Qb + (size_t)(qw + qs*16 + l15) * SR;
#pragma unroll
    for (int es = 0; es < 2; ++es) {
      f4 a = *(const f4*)(qp0 + es*32 + g*8);
      f4 c = *(const f4*)(qp0 + es*32 + g*8 + 4);
      h8 q_;
#pragma unroll
      for (int i = 0; i < 8; ++i)
        q_[i] = (_Float16)(((i < 4) ? a[i] : c[i-4]) * SC);
      qf[qs][es] = q_;
    }
  }

  f4 accO[4][2];                                    // O^T tiles [d-tile][qs]
#pragma unroll
  for (int t = 0; t < 4; ++t)
#pragma unroll
    for (int qs = 0; qs < 2; ++qs)
      accO[t][qs] = (f4){0.f, 0.f, 0.f, 0.f};
  float m_run[2] = {-1e30f, -1e30f};
  float l_run[2] = {0.f, 0.f};

  const int nt = (q0 + QB) >> 6;

  for (int kt = 0; kt < nt; ++kt) {
    const int k0 = kt << 6;
    __syncthreads();
    // -------- stage K rows (f16, row-major) + V^T (f16, d-major) --------
#pragma unroll
    for (int rep = 0; rep < 2; ++rep) {
      const int idx = tid + rep*256;                // 0..511
      // K: unit = (row r, 8-col chunk c8)
      const int r = idx >> 3, c8 = idx & 7;
      const float* kp = Kb + (size_t)(k0 + r) * SR + c8*8;
      f4 ka = *(const f4*)kp, kc = *(const f4*)(kp + 4);
      h8 kh;
#pragma unroll
      for (int i = 0; i < 8; ++i)
        kh[i] = (_Float16)((i < 4) ? ka[i] : kc[i-4]);
      *(h8*)(smem + OFF_K + r*KROWB + c8*16) = kh;
      // V^T: unit = (s-pair s2, 4-col chunk c4); pack (s,s+1) f16 pair per u32
      const int s2 = idx >> 4, c4 = idx & 15;
      const float* vp0 = Vb + (size_t)(k0 + 2*s2) * SR + c4*4;
      f4 v0 = *(const f4*)vp0;
      f4 v1 = *(const f4*)(vp0 + SR);
#pragma unroll
      for (int i = 0; i < 4; ++i) {
        union { _Float16 hh[2]; unsigned int uu; } pk;
        pk.hh[0] = (_Float16)v0[i];
        pk.hh[1] = (_Float16)v1[i];
        *(unsigned int*)(smem + OFF_V + (c4*4 + i)*VTS + s2*4) = pk.uu;
      }
    }
    __syncthreads();
    if (k0 > qmaxw) continue;                       // barrier counts still match

    // -------- QK^T swapped: D[key][q], A=K B=Q (k-slot maps cancel) --------
    f4 acc[4][2];
#pragma unroll
    for (int ks = 0; ks < 4; ++ks) {
      if (k0 + 16*ks > qmaxw) continue;
      h8 kf[2];
#pragma unroll
      for (int es = 0; es < 2; ++es)
        kf[es] = *(const h8*)(smem + OFF_K + (16*ks + l15)*KROWB + es*64 + g*16);
#pragma unroll
      for (int qs = 0; qs < 2; ++qs) {
        if (k0 + 16*ks > qw + 16*qs + 15) continue;
        f4 a = (f4){0.f, 0.f, 0.f, 0.f};
        a = __builtin_amdgcn_mfma_f32_16x16x32_f16(kf[0], qf[qs][0], a, 0, 0, 0);
        a = __builtin_amdgcn_mfma_f32_16x16x32_f16(kf[1], qf[qs][1], a, 0, 0, 0);
        if (k0 + 16*ks + 15 > qw + 16*qs) {         // causal boundary mask
          const int kb_  = k0 + 16*ks + 4*g;        // C/D row = key (m89 layout)
          const int qrow = qw + 16*qs + l15;        // C/D col = q
#pragma unroll
          for (int r = 0; r < 4; ++r)
            if (kb_ + r > qrow) a[r] = -1e30f;
        }
        acc[ks][qs] = a;
      }
    }

    // -------- online softmax (per q = lane&15 column) --------
    h4 pf[2][4];                                    // [qs][ks] P frags (f16)
#pragma unroll
    for (int qs = 0; qs < 2; ++qs) {
      if (k0 > qw + 16*qs + 15) continue;
      float mx = -1e30f;
#pragma unroll
      for (int ks = 0; ks < 4; ++ks) {
        if (k0 + 16*ks > qw + 16*qs + 15) continue;
        mx = fmaxf(mx, fmaxf(fmaxf(acc[ks][qs][0], acc[ks][qs][1]),
                             fmaxf(acc[ks][qs][2], acc[ks][qs][3])));
      }
      mx = fmaxf(mx, __shfl_xor(mx, 16));
      mx = fmaxf(mx, __shfl_xor(mx, 32));
      const float mnew = fmaxf(m_run[qs], mx);
      const float fsc  = EXP2F(m_run[qs] - mnew);
      m_run[qs] = mnew;
      float ps = 0.f;
#pragma unroll
      for (int ks = 0; ks < 4; ++ks) {
        if (k0 + 16*ks > qw + 16*qs + 15) continue;
        const float p0 = EXP2F(acc[ks][qs][0] - mnew);
        const float p1 = EXP2F(acc[ks][qs][1] - mnew);
        const float p2 = EXP2F(acc[ks][qs][2] - mnew);
        const float p3 = EXP2F(acc[ks][qs][3] - mnew);
        ps += (p0 + p1) + (p2 + p3);
        h4 pk;
        pk[0] = (_Float16)p0; pk[1] = (_Float16)p1;
        pk[2] = (_Float16)p2; pk[3] = (_Float16)p3;
        pf[qs][ks] = pk;
      }
      ps += __shfl_xor(ps, 16);
      ps += __shfl_xor(ps, 32);
      l_run[qs] = l_run[qs] * fsc + ps;
#pragma unroll
      for (int t = 0; t < 4; ++t) accO[t][qs] *= fsc;
    }

    // -------- PV swapped: D[d][q], A=V^T (plain 8B reads), B=P --------
    h4 vf[4][4];                                    // [s-chunk][d-tile]
#pragma unroll
    for (int c = 0; c < 4; ++c) {
      if (k0 + 16*c > qmaxw) continue;
#pragma unroll
      for (int t = 0; t < 4; ++t)
        vf[c][t] = *(const h4*)(smem + OFF_V + (16*t + l15)*VTS + (16*c + 4*g)*2);
    }
#pragma unroll
    for (int qs = 0; qs < 2; ++qs) {
#pragma unroll
      for (int c = 0; c < 4; ++c) {
        if (k0 + 16*c > qw + 16*qs + 15) continue;
#pragma unroll
        for (int t = 0; t < 4; ++t)
          accO[t][qs] = __builtin_amdgcn_mfma_f32_16x16x16f16(vf[c][t], pf[qs][c],
                                                              accO[t][qs], 0, 0, 0);
      }
    }
  } // k-tiles

  // -------- epilogue: normalize, LDS bounce, coalesced fp32 stores --------
  const unsigned ob = OFF_OB + (unsigned)w * OBSZ;
#pragma unroll
  for (int qs = 0; qs < 2; ++qs) {
    const float inv = 1.0f / l_run[qs];
#pragma unroll
    for (int t = 0; t < 4; ++t)
#pragma unroll
      for (int r = 0; r < 4; ++r) {
        const int d = 16*t + 4*g + r;
        *(float*)(smem + ob + l15*OBSTR + d*4) = accO[t][qs][r] * inv;
      }
    // same-wave LDS RAW: compiler orders via lgkmcnt
#pragma unroll
    for (int p = 0; p < 4; ++p) {
      f4 ov = *(const f4*)(smem + ob + (p*4 + g)*OBSTR + l15*16);
      *(f4*)(Ob + (size_t)(qw + qs*16 + p*4 + g) * SR + l15*4) = ov;
    }
  }
}

extern "C" void kernel_launch(void* const* d_in, const int* in_sizes, int n_in,
                              void* d_out, int out_size, void* d_ws, size_t ws_size,
                              hipStream_t stream) {
  const float* Q = (const float*)d_in[0];
  const float* K = (const float*)d_in[1];
  const float* V = (const float*)d_in[2];
  float* O = (float*)d_out;
  (void)in_sizes; (void)n_in; (void)out_size; (void)d_ws; (void)ws_size;
  dim3 grid(512), block(256);
  hipLaunchKernelGGL(fa_fwd_causal, grid, block, 0, stream, Q, K, V, O);
}

// Round 12
// 141.018 us; speedup vs baseline: 1.2962x; 1.2962x over previous
//
#include <hip/hip_runtime.h>

typedef _Float16 h4 __attribute__((ext_vector_type(4)));
typedef _Float16 h8 __attribute__((ext_vector_type(8)));
typedef float    f4 __attribute__((ext_vector_type(4)));

#define EXP2F(x) __builtin_amdgcn_exp2f(x)

#define L_   2048
#define SR   512      // H*E row stride (elements)
#define QB   128      // q rows per block
#define QW   16       // q rows per wave (8 waves/block)

// ---- LDS layout (bytes) ----
#define OFF_K   0
#define KROWB   144                       // 64 f16 + 16 pad per K row
#define OFF_V   (64*KROWB)                // 9216
#define VTS     136                       // V^T row stride: 64 f16 + 8 pad
#define OFF_OB  (OFF_V + 64*VTS)          // 17920
#define OBSTR   272                       // 64 floats + 16B pad per q row
#define OBSZ    (16*OBSTR)                // 4352 per wave
#define LDS_TOTAL (OFF_OB + 8*OBSZ)       // 52736

__global__ __launch_bounds__(512, 4)
void fa_fwd_causal(const float* __restrict__ Qg, const float* __restrict__ Kg,
                   const float* __restrict__ Vg, float* __restrict__ Og) {
  __shared__ char smem[LDS_TOTAL] __attribute__((aligned(16)));

  // big causal tiles first; bx and bx+256 co-resident pairs have uniform
  // total work: qt(u) + qt(u+8) == 15.
  const int bx = blockIdx.x;
  const int u  = bx >> 5;
  const int qt = (u < 8) ? (15 - 2*u) : (2*u - 16);
  const int bh = bx & 31;
  const int b  = bh >> 3, h = bh & 7;
  const int q0 = qt * QB;

  const int tid = threadIdx.x, lane = tid & 63, w = tid >> 6;   // w: 0..7
  const int l15 = lane & 15, g = lane >> 4;

  const size_t base = (size_t)b * (L_ * SR) + (size_t)h * 64;
  const float* Qb = Qg + base;
  const float* Kb = Kg + base;
  const float* Vb = Vg + base;
  float*       Ob = Og + base;

  const int qw0   = q0 + w * QW;          // wave's 16 q-rows
  const int qrow  = qw0 + l15;
  const int qmaxw = qw0 + 15;

  // ---- Q frags: fp32 -> f16, scale*log2(e) folded in ----
  const float SC = 0.125f * 1.44269504088896340736f;
  h8 qf[2];                                         // [es]
#pragma unroll
  for (int es = 0; es < 2; ++es) {
    const float* qp = Qb + (size_t)qrow * SR + es*32 + g*8;
    f4 a = *(const f4*)qp;
    f4 c = *(const f4*)(qp + 4);
    h8 q_;
#pragma unroll
    for (int i = 0; i < 8; ++i)
      q_[i] = (_Float16)(((i < 4) ? a[i] : c[i-4]) * SC);
    qf[es] = q_;
  }

  f4 accO[4];                                       // O^T tiles [d-tile]
#pragma unroll
  for (int t = 0; t < 4; ++t) accO[t] = (f4){0.f, 0.f, 0.f, 0.f};
  float m_run = -1e30f, l_run = 0.f;

  const int nt = (q0 + QB) >> 6;

  for (int kt = 0; kt < nt; ++kt) {
    const int k0 = kt << 6;
    __syncthreads();
    // -------- stage K rows (f16) + V^T (f16): one unit per thread --------
    {
      // K: unit = (row r, 8-col chunk c8)
      const int r = tid >> 3, c8 = tid & 7;
      const float* kp = Kb + (size_t)(k0 + r) * SR + c8*8;
      f4 ka = *(const f4*)kp, kc = *(const f4*)(kp + 4);
      h8 kh;
#pragma unroll
      for (int i = 0; i < 8; ++i)
        kh[i] = (_Float16)((i < 4) ? ka[i] : kc[i-4]);
      *(h8*)(smem + OFF_K + r*KROWB + c8*16) = kh;
      // V^T: unit = (s-pair s2, 4-col chunk c4)
      const int s2 = tid >> 4, c4 = tid & 15;
      const float* vp0 = Vb + (size_t)(k0 + 2*s2) * SR + c4*4;
      f4 v0 = *(const f4*)vp0;
      f4 v1 = *(const f4*)(vp0 + SR);
#pragma unroll
      for (int i = 0; i < 4; ++i) {
        union { _Float16 hh[2]; unsigned int uu; } pk;
        pk.hh[0] = (_Float16)v0[i];
        pk.hh[1] = (_Float16)v1[i];
        *(unsigned int*)(smem + OFF_V + (c4*4 + i)*VTS + s2*4) = pk.uu;
      }
    }
    __syncthreads();
    if (k0 > qmaxw) continue;                       // barrier counts still match

    // -------- QK^T swapped: D[key][q], A=K B=Q --------
    f4 acc[4];
#pragma unroll
    for (int ks = 0; ks < 4; ++ks) {
      if (k0 + 16*ks > qmaxw) continue;
      h8 kf0 = *(const h8*)(smem + OFF_K + (16*ks + l15)*KROWB + g*16);
      h8 kf1 = *(const h8*)(smem + OFF_K + (16*ks + l15)*KROWB + 64 + g*16);
      f4 a = (f4){0.f, 0.f, 0.f, 0.f};
      a = __builtin_amdgcn_mfma_f32_16x16x32_f16(kf0, qf[0], a, 0, 0, 0);
      a = __builtin_amdgcn_mfma_f32_16x16x32_f16(kf1, qf[1], a, 0, 0, 0);
      if (k0 + 16*ks + 15 > qw0) {                  // causal boundary mask
        const int kb_ = k0 + 16*ks + 4*g;           // C/D row = key (m89)
#pragma unroll
        for (int r = 0; r < 4; ++r)
          if (kb_ + r > qrow) a[r] = -1e30f;
      }
      acc[ks] = a;
    }

    // -------- online softmax (per q = lane&15 column) --------
    float mx = -1e30f;
#pragma unroll
    for (int ks = 0; ks < 4; ++ks) {
      if (k0 + 16*ks > qmaxw) continue;
      mx = fmaxf(mx, fmaxf(fmaxf(acc[ks][0], acc[ks][1]),
                           fmaxf(acc[ks][2], acc[ks][3])));
    }
    mx = fmaxf(mx, __shfl_xor(mx, 16));
    mx = fmaxf(mx, __shfl_xor(mx, 32));
    const float mnew = fmaxf(m_run, mx);
    const float fsc  = EXP2F(m_run - mnew);
    m_run = mnew;
    float ps = 0.f;
    h4 pf[4];
#pragma unroll
    for (int ks = 0; ks < 4; ++ks) {
      if (k0 + 16*ks > qmaxw) continue;
      const float p0 = EXP2F(acc[ks][0] - mnew);
      const float p1 = EXP2F(acc[ks][1] - mnew);
      const float p2 = EXP2F(acc[ks][2] - mnew);
      const float p3 = EXP2F(acc[ks][3] - mnew);
      ps += (p0 + p1) + (p2 + p3);
      h4 pk;
      pk[0] = (_Float16)p0; pk[1] = (_Float16)p1;
      pk[2] = (_Float16)p2; pk[3] = (_Float16)p3;
      pf[ks] = pk;
    }
    ps += __shfl_xor(ps, 16);
    ps += __shfl_xor(ps, 32);
    l_run = l_run * fsc + ps;
#pragma unroll
    for (int t = 0; t < 4; ++t) accO[t] *= fsc;

    // -------- PV swapped: D[d][q], A=V^T, B=P --------
    h4 vf[4][4];                                    // [s-chunk][d-tile]
#pragma unroll
    for (int c = 0; c < 4; ++c) {
      if (k0 + 16*c > qmaxw) continue;
#pragma unroll
      for (int t = 0; t < 4; ++t)
        vf[c][t] = *(const h4*)(smem + OFF_V + (16*t + l15)*VTS + (16*c + 4*g)*2);
    }
#pragma unroll
    for (int c = 0; c < 4; ++c) {
      if (k0 + 16*c > qmaxw) continue;
#pragma unroll
      for (int t = 0; t < 4; ++t)
        accO[t] = __builtin_amdgcn_mfma_f32_16x16x16f16(vf[c][t], pf[c],
                                                        accO[t], 0, 0, 0);
    }
  } // k-tiles

  // -------- epilogue: normalize, LDS bounce, coalesced fp32 stores --------
  const unsigned ob = OFF_OB + (unsigned)w * OBSZ;  // per-wave region: no race
  const float inv = 1.0f / l_run;
#pragma unroll
  for (int t = 0; t < 4; ++t)
#pragma unroll
    for (int r = 0; r < 4; ++r) {
      const int d = 16*t + 4*g + r;
      *(float*)(smem + ob + l15*OBSTR + d*4) = accO[t][r] * inv;
    }
  // same-wave LDS RAW: compiler orders via lgkmcnt
#pragma unroll
  for (int p = 0; p < 4; ++p) {
    f4 ov = *(const f4*)(smem + ob + (p*4 + g)*OBSTR + l15*16);
    *(f4*)(Ob + (size_t)(qw0 + p*4 + g) * SR + l15*4) = ov;
  }
}

extern "C" void kernel_launch(void* const* d_in, const int* in_sizes, int n_in,
                              void* d_out, int out_size, void* d_ws, size_t ws_size,
                              hipStream_t stream) {
  const float* Q = (const float*)d_in[0];
  const float* K = (const float*)d_in[1];
  const float* V = (const float*)d_in[2];
  float* O = (float*)d_out;
  (void)in_sizes; (void)n_in; (void)out_size; (void)d_ws; (void)ws_size;
  dim3 grid(512), block(512);
  hipLaunchKernelGGL(fa_fwd_causal, grid, block, 0, stream, Q, K, V, O);
}

// Round 14
// 127.540 us; speedup vs baseline: 1.4332x; 1.1057x over previous
//
#include <hip/hip_runtime.h>

typedef _Float16 h4 __attribute__((ext_vector_type(4)));
typedef _Float16 h8 __attribute__((ext_vector_type(8)));
typedef float    f4 __attribute__((ext_vector_type(4)));

#define EXP2F(x) __builtin_amdgcn_exp2f(x)

#define L_   2048
#define SR   512      // H*E row stride (elements)
#define QB   128      // q rows per block
#define QW   16       // q rows per wave (8 waves/block)

// ---- LDS layout (bytes) ----
#define OFF_K   0
#define KROWB   144                       // 64 f16 + 16 pad per K row
#define OFF_V   (64*KROWB)                // 9216
#define VTS     136                       // V^T row stride: 64 f16 + 8 pad
#define OFF_OB  (OFF_V + 64*VTS)          // 17920
#define OBSTR   272                       // 64 floats + 16B pad per q row
#define OBSZ    (16*OBSTR)                // 4352 per wave
#define LDS_TOTAL (OFF_OB + 8*OBSZ)       // 52736

__global__ __launch_bounds__(512, 4)
void fa_fwd_causal(const float* __restrict__ Qg, const float* __restrict__ Kg,
                   const float* __restrict__ Vg, float* __restrict__ Og) {
  __shared__ char smem[LDS_TOTAL] __attribute__((aligned(16)));

  // big causal tiles first; bx and bx+256 pairs have uniform total work.
  const int bx = blockIdx.x;
  const int u  = bx >> 5;
  const int qt = (u < 8) ? (15 - 2*u) : (2*u - 16);
  const int bh = bx & 31;
  const int b  = bh >> 3, h = bh & 7;
  const int q0 = qt * QB;

  const int tid = threadIdx.x, lane = tid & 63, w = tid >> 6;   // w: 0..7
  const int l15 = lane & 15, g = lane >> 4;

  const size_t base = (size_t)b * (L_ * SR) + (size_t)h * 64;
  const float* Qb = Qg + base;
  const float* Kb = Kg + base;
  const float* Vb = Vg + base;
  float*       Ob = Og + base;

  const int qw0   = q0 + w * QW;          // wave's 16 q-rows
  const int qrow  = qw0 + l15;
  const int qmaxw = qw0 + 15;

  // ---- Q frags: fp32 -> f16, scale*log2(e) folded in ----
  const float SC = 0.125f * 1.44269504088896340736f;
  h8 qf[2];                                         // [es]
#pragma unroll
  for (int es = 0; es < 2; ++es) {
    const float* qp = Qb + (size_t)qrow * SR + es*32 + g*8;
    f4 a = *(const f4*)qp;
    f4 c = *(const f4*)(qp + 4);
    h8 q_;
#pragma unroll
    for (int i = 0; i < 8; ++i)
      q_[i] = (_Float16)(((i < 4) ? a[i] : c[i-4]) * SC);
    qf[es] = q_;
  }

  f4 accO[4];                                       // O^T tiles [d-tile]
#pragma unroll
  for (int t = 0; t < 4; ++t) accO[t] = (f4){0.f, 0.f, 0.f, 0.f};
  float m_run = -1e30f, l_run = 0.f;

  const int nt = (q0 + QB) >> 6;

  // ---- T14 async-STAGE: per-thread staging units + prefetch registers ----
  const int r  = tid >> 3, c8 = tid & 7;            // K unit: row r, chunk c8
  const int s2 = tid >> 4, c4 = tid & 15;           // V unit: s-pair s2, chunk c4
  const float* kp_base = Kb + (size_t)r * SR + c8*8;
  const float* vp_base = Vb + (size_t)(2*s2) * SR + c4*4;

  f4 pka, pkc, pv0, pv1;                            // prefetched tile (fp32)
  pka = *(const f4*)(kp_base);                      // prologue: tile 0
  pkc = *(const f4*)(kp_base + 4);
  pv0 = *(const f4*)(vp_base);
  pv1 = *(const f4*)(vp_base + SR);

  for (int kt = 0; kt < nt; ++kt) {
    const int k0 = kt << 6;
    __syncthreads();                                // prev tile's readers done
    // -------- stage K + V^T into LDS from prefetch regs --------
    {
      h8 kh;
#pragma unroll
      for (int i = 0; i < 8; ++i)
        kh[i] = (_Float16)((i < 4) ? pka[i] : pkc[i-4]);
      *(h8*)(smem + OFF_K + r*KROWB + c8*16) = kh;
#pragma unroll
      for (int i = 0; i < 4; ++i) {
        union { _Float16 hh[2]; unsigned int uu; } pk;
        pk.hh[0] = (_Float16)pv0[i];
        pk.hh[1] = (_Float16)pv1[i];
        *(unsigned int*)(smem + OFF_V + (c4*4 + i)*VTS + s2*4) = pk.uu;
      }
    }
    __syncthreads();                                // staging visible
    // -------- issue next tile's global loads (latency hides under compute) --------
    if (kt + 1 < nt) {
      const float* kp = kp_base + (size_t)(k0 + 64) * SR;
      const float* vp = vp_base + (size_t)(k0 + 64) * SR;
      pka = *(const f4*)(kp);
      pkc = *(const f4*)(kp + 4);
      pv0 = *(const f4*)(vp);
      pv1 = *(const f4*)(vp + SR);
    }
    if (k0 > qmaxw) continue;                       // barrier counts still match

    // -------- QK^T swapped: D[key][q], A=K B=Q --------
    f4 acc[4];
#pragma unroll
    for (int ks = 0; ks < 4; ++ks) {
      if (k0 + 16*ks > qmaxw) continue;
      h8 kf0 = *(const h8*)(smem + OFF_K + (16*ks + l15)*KROWB + g*16);
      h8 kf1 = *(const h8*)(smem + OFF_K + (16*ks + l15)*KROWB + 64 + g*16);
      f4 a = (f4){0.f, 0.f, 0.f, 0.f};
      a = __builtin_amdgcn_mfma_f32_16x16x32_f16(kf0, qf[0], a, 0, 0, 0);
      a = __builtin_amdgcn_mfma_f32_16x16x32_f16(kf1, qf[1], a, 0, 0, 0);
      if (k0 + 16*ks + 15 > qw0) {                  // causal boundary mask
        const int kb_ = k0 + 16*ks + 4*g;           // C/D row = key (m89)
#pragma unroll
        for (int rr = 0; rr < 4; ++rr)
          if (kb_ + rr > qrow) a[rr] = -1e30f;
      }
      acc[ks] = a;
    }

    // -------- online softmax (per q = lane&15 column) --------
    float mx = -1e30f;
#pragma unroll
    for (int ks = 0; ks < 4; ++ks) {
      if (k0 + 16*ks > qmaxw) continue;
      mx = fmaxf(mx, fmaxf(fmaxf(acc[ks][0], acc[ks][1]),
                           fmaxf(acc[ks][2], acc[ks][3])));
    }
    mx = fmaxf(mx, __shfl_xor(mx, 16));
    mx = fmaxf(mx, __shfl_xor(mx, 32));
    const float mnew = fmaxf(m_run, mx);
    const float fsc  = EXP2F(m_run - mnew);
    m_run = mnew;
    float ps = 0.f;
    h4 pf[4];
#pragma unroll
    for (int ks = 0; ks < 4; ++ks) {
      if (k0 + 16*ks > qmaxw) continue;
      const float p0 = EXP2F(acc[ks][0] - mnew);
      const float p1 = EXP2F(acc[ks][1] - mnew);
      const float p2 = EXP2F(acc[ks][2] - mnew);
      const float p3 = EXP2F(acc[ks][3] - mnew);
      ps += (p0 + p1) + (p2 + p3);
      h4 pk;
      pk[0] = (_Float16)p0; pk[1] = (_Float16)p1;
      pk[2] = (_Float16)p2; pk[3] = (_Float16)p3;
      pf[ks] = pk;
    }
    ps += __shfl_xor(ps, 16);
    ps += __shfl_xor(ps, 32);
    l_run = l_run * fsc + ps;
#pragma unroll
    for (int t = 0; t < 4; ++t) accO[t] *= fsc;

    // -------- PV swapped: D[d][q], A=V^T, B=P --------
    h4 vf[4][4];                                    // [s-chunk][d-tile]
#pragma unroll
    for (int c = 0; c < 4; ++c) {
      if (k0 + 16*c > qmaxw) continue;
#pragma unroll
      for (int t = 0; t < 4; ++t)
        vf[c][t] = *(const h4*)(smem + OFF_V + (16*t + l15)*VTS + (16*c + 4*g)*2);
    }
#pragma unroll
    for (int c = 0; c < 4; ++c) {
      if (k0 + 16*c > qmaxw) continue;
#pragma unroll
      for (int t = 0; t < 4; ++t)
        accO[t] = __builtin_amdgcn_mfma_f32_16x16x16f16(vf[c][t], pf[c],
                                                        accO[t], 0, 0, 0);
    }
  } // k-tiles

  // -------- epilogue: normalize, LDS bounce, coalesced fp32 stores --------
  const unsigned ob = OFF_OB + (unsigned)w * OBSZ;  // per-wave region: no race
  const float inv = 1.0f / l_run;
#pragma unroll
  for (int t = 0; t < 4; ++t)
#pragma unroll
    for (int rr = 0; rr < 4; ++rr) {
      const int d = 16*t + 4*g + rr;
      *(float*)(smem + ob + l15*OBSTR + d*4) = accO[t][rr] * inv;
    }
  // same-wave LDS RAW: compiler orders via lgkmcnt
#pragma unroll
  for (int p = 0; p < 4; ++p) {
    f4 ov = *(const f4*)(smem + ob + (p*4 + g)*OBSTR + l15*16);
    *(f4*)(Ob + (size_t)(qw0 + p*4 + g) * SR + l15*4) = ov;
  }
}

extern "C" void kernel_launch(void* const* d_in, const int* in_sizes, int n_in,
                              void* d_out, int out_size, void* d_ws, size_t ws_size,
                              hipStream_t stream) {
  const float* Q = (const float*)d_in[0];
  const float* K = (const float*)d_in[1];
  const float* V = (const float*)d_in[2];
  float* O = (float*)d_out;
  (void)in_sizes; (void)n_in; (void)out_size; (void)d_ws; (void)ws_size;
  dim3 grid(512), block(512);
  hipLaunchKernelGGL(fa_fwd_causal, grid, block, 0, stream, Q, K, V, O);
}